// Round 8
// baseline (113.899 us; speedup 1.0000x reference)
//
#include <hip/hip_runtime.h>

// Rel-pos attention, re-tiled MFMA design, r8. B=4, H=8, S=512, D=64.
//
// K1 qk_mfma : SK[b,h,s,t] = Q.K^T -> bf16 in d_ws (or fp32 in pout fallback).
// K2 attn_v7 : one block per (b,s). Stage R[b,s] (512x64) -> LDS bf16 ONCE.
//              rel = Q.R^T (MFMA) -> Sb; softmax((rel+SK)/8, mask) -> p;
//              ans2 = P.R (MFMA) -> ans.   R read exactly once from HBM.
// K3 pv_mfma : one block per (b,h,s-tile32), grid 512 -> 2 blocks/CU.
//              Stage V[b,h] -> LDS bf16; ans += P.V (MFMA), P from pout.
//
// LDS swizzle slot(t) = (t&7)^((t>>3)&7) XORed into bits 3..5 of the u16
// index (see r7 — proven).

typedef __attribute__((ext_vector_type(8))) short short8;
typedef __attribute__((ext_vector_type(4))) float f32x4;

#define MFMA16(a, b, c) __builtin_amdgcn_mfma_f32_16x16x32_bf16(a, b, c, 0, 0, 0)

__device__ __forceinline__ unsigned short f2bf(float x) {
  unsigned int u = __float_as_uint(x);
  u += 0x7fffu + ((u >> 16) & 1u);   // RNE
  return (unsigned short)(u >> 16);
}
__device__ __forceinline__ float bf2f(unsigned int s) {
  return __uint_as_float(s << 16);
}
__device__ __forceinline__ short8 pack8(const float4& a, const float4& b) {
  short8 r;
  r[0] = (short)f2bf(a.x); r[1] = (short)f2bf(a.y);
  r[2] = (short)f2bf(a.z); r[3] = (short)f2bf(a.w);
  r[4] = (short)f2bf(b.x); r[5] = (short)f2bf(b.y);
  r[6] = (short)f2bf(b.z); r[7] = (short)f2bf(b.w);
  return r;
}
__device__ __forceinline__ int RLI(int t, int d) {
  return ((t << 6) | d) ^ ((((t & 7) ^ ((t >> 3) & 7))) << 3);
}
__device__ __forceinline__ int SBI(int h, int t) {
  return ((h << 9) | t) ^ ((h & 7) << 3);
}

// ---------------- K1: SK = Q.K^T per (b,h), 64x64 tiles -------------------
template <bool WSK>
__global__ __launch_bounds__(256, 4)
void qk_mfma(const float* __restrict__ Q, const float* __restrict__ K,
             void* __restrict__ skout) {
  const int bh   = blockIdx.x >> 6;
  const int tile = blockIdx.x & 63;
  const int s0 = (tile >> 3) << 6;
  const int t0 = (tile & 7) << 6;
  const int w    = threadIdx.x >> 6;
  const int lane = threadIdx.x & 63;
  const int rrow = lane & 15;
  const int kg   = lane >> 4;

  const float* Qb = Q + ((size_t)bh << 15);
  const float* Kb = K + ((size_t)bh << 15);

  const float* qp = Qb + (((s0 + (w << 4) + rrow) << 6) + (kg << 3));
  const short8 a0 = pack8(*reinterpret_cast<const float4*>(qp),
                          *reinterpret_cast<const float4*>(qp + 4));
  const short8 a1 = pack8(*reinterpret_cast<const float4*>(qp + 32),
                          *reinterpret_cast<const float4*>(qp + 36));

  float4 b0, b1, b2, b3;
  {
    const float* kp = Kb + (((t0 + rrow) << 6) + (kg << 3));
    b0 = *reinterpret_cast<const float4*>(kp);
    b1 = *reinterpret_cast<const float4*>(kp + 4);
    b2 = *reinterpret_cast<const float4*>(kp + 32);
    b3 = *reinterpret_cast<const float4*>(kp + 36);
  }
#pragma unroll
  for (int nt = 0; nt < 4; ++nt) {
    const short8 bb0 = pack8(b0, b1);
    const short8 bb1 = pack8(b2, b3);
    if (nt < 3) {
      const float* kp = Kb + (((t0 + ((nt + 1) << 4) + rrow) << 6) + (kg << 3));
      b0 = *reinterpret_cast<const float4*>(kp);
      b1 = *reinterpret_cast<const float4*>(kp + 4);
      b2 = *reinterpret_cast<const float4*>(kp + 32);
      b3 = *reinterpret_cast<const float4*>(kp + 36);
    }
    f32x4 c = {0.0f, 0.0f, 0.0f, 0.0f};
    c = MFMA16(a0, bb0, c);
    c = MFMA16(a1, bb1, c);
    const int tcol = t0 + (nt << 4) + rrow;
    const int srow = s0 + (w << 4) + (kg << 2);
    if constexpr (WSK) {
      unsigned short* ob = (unsigned short*)skout + ((size_t)bh << 18);
#pragma unroll
      for (int r = 0; r < 4; ++r)
        ob[(size_t)(srow + r) * 512 + tcol] = f2bf(c[r]);
    } else {
      float* ob = (float*)skout + ((size_t)bh << 18);
#pragma unroll
      for (int r = 0; r < 4; ++r)
        ob[(size_t)(srow + r) * 512 + tcol] = c[r];
    }
  }
}

// ---------------- K2: per (b,s): rel + softmax + ans2 ---------------------
template <bool WSK>
__global__ __launch_bounds__(256, 2)
void attn_v7k(const float* __restrict__ Q, const float* __restrict__ R,
              const int* __restrict__ Mk, float* __restrict__ ans,
              float* __restrict__ pout, const void* __restrict__ skin) {
  __shared__ __align__(16) unsigned short smem[8 * 512 + 512 * 64];  // 72 KB
  unsigned short* Sb = smem;
  unsigned short* Rl = smem + 8 * 512;

  const int tid = threadIdx.x;
  const int b = blockIdx.x >> 9;
  const int s = blockIdx.x & 511;
  const int bh0 = b << 3;

  const float* Rg = R + ((size_t)((b << 9) + s) << 15);

  // ---- stage R[b,s] 512x64 fp32 -> Rl bf16 (swizzled), 8-deep batches ----
  {
    const int c16 = tid & 15;
    const int r0  = tid >> 4;
#pragma unroll
    for (int pg = 0; pg < 4; ++pg) {
      float4 tmp[8];
#pragma unroll
      for (int j = 0; j < 8; ++j) {
        const int t = (((pg << 3) + j) << 4) + r0;
        tmp[j] = *reinterpret_cast<const float4*>(Rg + (t << 6) + (c16 << 2));
      }
#pragma unroll
      for (int j = 0; j < 8; ++j) {
        const int t = (((pg << 3) + j) << 4) + r0;
        unsigned short* dst = &Rl[RLI(t, c16 << 2)];
        dst[0] = f2bf(tmp[j].x); dst[1] = f2bf(tmp[j].y);
        dst[2] = f2bf(tmp[j].z); dst[3] = f2bf(tmp[j].w);
      }
    }
  }
  __syncthreads();

  const int lane = tid & 63;
  const int w    = tid >> 6;
  const int nn   = lane & 15;
  const int kg   = lane >> 4;

  // ---- rel[h,t] = Q[h,:].R[t,:] (A=Q padded to 16 rows, B=R) -> Sb ----
  {
    const int hq = nn & 7;
    const float* Qg = Q + ((size_t)(((bh0 + hq) << 9) + s) << 6);
    const short8 aq0 = pack8(*reinterpret_cast<const float4*>(Qg + (kg << 3)),
                             *reinterpret_cast<const float4*>(Qg + (kg << 3) + 4));
    const short8 aq1 = pack8(*reinterpret_cast<const float4*>(Qg + 32 + (kg << 3)),
                             *reinterpret_cast<const float4*>(Qg + 36 + (kg << 3)));

#pragma unroll
    for (int i = 0; i < 8; ++i) {
      const int t0 = ((w << 3) + i) << 4;
      const short8 bb0 = *reinterpret_cast<const short8*>(&Rl[RLI(t0 + nn, kg << 3)]);
      const short8 bb1 = *reinterpret_cast<const short8*>(&Rl[RLI(t0 + nn, 32 + (kg << 3))]);
      f32x4 c = {0.0f, 0.0f, 0.0f, 0.0f};
      c = MFMA16(aq0, bb0, c);
      c = MFMA16(aq1, bb1, c);
      if (kg < 2) {
#pragma unroll
        for (int r = 0; r < 4; ++r)
          Sb[SBI((kg << 2) + r, t0 + nn)] = f2bf(c[r]);
      }
    }
  }
  __syncthreads();

  // ---- softmax rows h = 2w,2w+1: (rel + SK)/8 + mask -> p ----
  {
    float bias[8];
#pragma unroll
    for (int k = 0; k < 8; ++k)
      bias[k] = Mk[(b << 9) + lane + (k << 6)] ? 0.0f : -1.0e9f;

#pragma unroll
    for (int rr = 0; rr < 2; ++rr) {
      const int h = (w << 1) + rr;
      float* po = pout + ((size_t)(bh0 + h) << 18) + ((size_t)s << 9);
      const unsigned short* skw =
          WSK ? (const unsigned short*)skin + ((size_t)(bh0 + h) << 18) + ((size_t)s << 9)
              : nullptr;
      const float* skf =
          WSK ? nullptr
              : (const float*)skin + ((size_t)(bh0 + h) << 18) + ((size_t)s << 9);

      float v[8];
#pragma unroll
      for (int k = 0; k < 8; ++k) {
        const int t = lane + (k << 6);
        const float skv = WSK ? bf2f((unsigned int)skw[t]) : skf[t];
        v[k] = (bf2f((unsigned int)Sb[SBI(h, t)]) + skv) * 0.125f + bias[k];
      }
      float m = v[0];
#pragma unroll
      for (int k = 1; k < 8; ++k) m = fmaxf(m, v[k]);
      m = fmaxf(m, __shfl_xor(m, 1));
      m = fmaxf(m, __shfl_xor(m, 2));
      m = fmaxf(m, __shfl_xor(m, 4));
      m = fmaxf(m, __shfl_xor(m, 8));
      m = fmaxf(m, __shfl_xor(m, 16));
      m = fmaxf(m, __shfl_xor(m, 32));

      float e[8], ss = 0.0f;
#pragma unroll
      for (int k = 0; k < 8; ++k) { e[k] = __expf(v[k] - m); ss += e[k]; }
      ss += __shfl_xor(ss, 1);
      ss += __shfl_xor(ss, 2);
      ss += __shfl_xor(ss, 4);
      ss += __shfl_xor(ss, 8);
      ss += __shfl_xor(ss, 16);
      ss += __shfl_xor(ss, 32);
      const float inv = 1.0f / ss;

#pragma unroll
      for (int k = 0; k < 8; ++k) {
        const float p = e[k] * inv;
        const int t = lane + (k << 6);
        po[t] = p;
        Sb[SBI(h, t)] = f2bf(p);
      }
    }
  }
  __syncthreads();

  // ---- ans2[h,d] = sum_t P[h,t].R[t,d], wave w: d-tile w*16 ----
  {
    const int n0 = w << 4;
    f32x4 acc = {0.0f, 0.0f, 0.0f, 0.0f};
#pragma unroll
    for (int ks = 0; ks < 16; ++ks) {
      const int tb = (ks << 5) + (kg << 3);
      const short8 af = *reinterpret_cast<const short8*>(&Sb[SBI(nn, tb)]);
      short8 bf;
#pragma unroll
      for (int j = 0; j < 8; ++j)
        bf[j] = (short)Rl[RLI(tb + j, n0 + nn)];
      acc = MFMA16(af, bf, acc);
    }
    if (kg < 2) {
#pragma unroll
      for (int r = 0; r < 4; ++r) {
        const int h = (kg << 2) + r;
        ans[((size_t)(((bh0 + h) << 9) + s) << 6) + n0 + nn] = acc[r];
      }
    }
  }
}

// ---------------- K3: ans += P.V per (b,h,32-row s-tile), 2 blocks/CU -----
__global__ __launch_bounds__(256, 2)
void pv_mfma(const float* __restrict__ V, const float* __restrict__ pout,
             float* __restrict__ ans) {
  __shared__ __align__(16) unsigned short Vl[512 * 64];   // 64 KB

  const int tid = threadIdx.x;
  const int bh = blockIdx.x >> 4;
  const int s0 = (blockIdx.x & 15) << 5;

  const float* Vg = V + ((size_t)bh << 15);
  {
    const int c16 = tid & 15;
    const int r0  = tid >> 4;
#pragma unroll
    for (int pg = 0; pg < 4; ++pg) {
      float4 tmp[8];
#pragma unroll
      for (int j = 0; j < 8; ++j) {
        const int t = (((pg << 3) + j) << 4) + r0;
        tmp[j] = *reinterpret_cast<const float4*>(Vg + (t << 6) + (c16 << 2));
      }
#pragma unroll
      for (int j = 0; j < 8; ++j) {
        const int t = (((pg << 3) + j) << 4) + r0;
        unsigned short* dst = &Vl[RLI(t, c16 << 2)];
        dst[0] = f2bf(tmp[j].x); dst[1] = f2bf(tmp[j].y);
        dst[2] = f2bf(tmp[j].z); dst[3] = f2bf(tmp[j].w);
      }
    }
  }
  __syncthreads();

  const int lane = tid & 63;
  const int w    = tid >> 6;
  const int nn   = lane & 15;
  const int kg   = lane >> 4;
  const int rw   = w & 1;        // s-subtile (16 rows)
  const int ch   = w >> 1;       // col half: d-cols ch*32 .. ch*32+31
  const int srow = s0 + (rw << 4) + nn;

  const float* Pg = pout + ((size_t)bh << 18) + ((size_t)srow << 9);

  f32x4 acc0 = {0.f, 0.f, 0.f, 0.f}, acc1 = acc0;

  float4 pa = *reinterpret_cast<const float4*>(Pg + (kg << 3));
  float4 pb = *reinterpret_cast<const float4*>(Pg + (kg << 3) + 4);
#pragma unroll
  for (int ks = 0; ks < 16; ++ks) {
    const short8 af = pack8(pa, pb);
    if (ks < 15) {
      pa = *reinterpret_cast<const float4*>(Pg + ((ks + 1) << 5) + (kg << 3));
      pb = *reinterpret_cast<const float4*>(Pg + ((ks + 1) << 5) + (kg << 3) + 4);
    }
    const int tb = (ks << 5) + (kg << 3);
    short8 b0, b1;
#pragma unroll
    for (int j = 0; j < 8; ++j) {
      b0[j] = (short)Vl[RLI(tb + j, (ch << 5) + nn)];
      b1[j] = (short)Vl[RLI(tb + j, (ch << 5) + 16 + nn)];
    }
    acc0 = MFMA16(af, b0, acc0);
    acc1 = MFMA16(af, b1, acc1);
  }

  {
    const int sb = s0 + (rw << 4) + (kg << 2);
#pragma unroll
    for (int r = 0; r < 4; ++r) {
      float* ap = ans + ((size_t)bh << 15) + ((size_t)(sb + r) << 6) + (ch << 5) + nn;
      ap[0]  += acc0[r];
      ap[16] += acc1[r];
    }
  }
}

extern "C" void kernel_launch(void* const* d_in, const int* in_sizes, int n_in,
                              void* d_out, int out_size, void* d_ws, size_t ws_size,
                              hipStream_t stream) {
  const float* Q  = (const float*)d_in[0];
  const float* K  = (const float*)d_in[1];
  const float* V  = (const float*)d_in[2];
  const float* R  = (const float*)d_in[3];
  const int*   Mk = (const int*)d_in[4];
  float* ans  = (float*)d_out;
  float* pout = ans + (size_t)4 * 8 * 512 * 64;  // p_attn region
  (void)in_sizes; (void)n_in; (void)out_size;

  const size_t sk_bf16_bytes = (size_t)4 * 8 * 512 * 512 * 2;  // 16.8 MB

  if (ws_size >= sk_bf16_bytes) {
    hipLaunchKernelGGL((qk_mfma<true>), dim3(2048), dim3(256), 0, stream,
                       Q, K, d_ws);
    hipLaunchKernelGGL((attn_v7k<true>), dim3(2048), dim3(256), 0, stream,
                       Q, R, Mk, ans, pout, d_ws);
  } else {
    hipLaunchKernelGGL((qk_mfma<false>), dim3(2048), dim3(256), 0, stream,
                       Q, K, pout);
    hipLaunchKernelGGL((attn_v7k<false>), dim3(2048), dim3(256), 0, stream,
                       Q, R, Mk, ans, pout, pout);
  }
  hipLaunchKernelGGL(pv_mfma, dim3(512), dim3(256), 0, stream, V, pout, ans);
}

// Round 9
// 111.517 us; speedup vs baseline: 1.0214x; 1.0214x over previous
//
#include <hip/hip_runtime.h>

// Rel-pos attention, re-tiled MFMA design, r9: K2/K3 widened to 512 threads
// (4 waves/SIMD instead of 2 — LDS-bound occupancy fixed by block width).
// B=4, H=8, S=512, D=64.
//
// K1 qk_mfma : SK[b,h,s,t] = Q.K^T -> bf16 in d_ws (or fp32 in pout fallback).
// K2 attn_v8 : one block per (b,s), 512 thr. Stage R[b,s] -> LDS bf16 ONCE.
//              rel = Q.R^T (MFMA) -> Sb; softmax((rel+SK)/8, mask) -> p;
//              ans2 = P.R (MFMA, 8-wave split + partial combine) -> ans.
// K3 pv_mfma : one block per (b,h,s-tile32), 512 thr. Stage V[b,h] -> LDS;
//              ans += P.V (MFMA), P streamed from pout.

typedef __attribute__((ext_vector_type(8))) short short8;
typedef __attribute__((ext_vector_type(4))) float f32x4;

#define MFMA16(a, b, c) __builtin_amdgcn_mfma_f32_16x16x32_bf16(a, b, c, 0, 0, 0)

__device__ __forceinline__ unsigned short f2bf(float x) {
  unsigned int u = __float_as_uint(x);
  u += 0x7fffu + ((u >> 16) & 1u);   // RNE
  return (unsigned short)(u >> 16);
}
__device__ __forceinline__ float bf2f(unsigned int s) {
  return __uint_as_float(s << 16);
}
__device__ __forceinline__ short8 pack8(const float4& a, const float4& b) {
  short8 r;
  r[0] = (short)f2bf(a.x); r[1] = (short)f2bf(a.y);
  r[2] = (short)f2bf(a.z); r[3] = (short)f2bf(a.w);
  r[4] = (short)f2bf(b.x); r[5] = (short)f2bf(b.y);
  r[6] = (short)f2bf(b.z); r[7] = (short)f2bf(b.w);
  return r;
}
__device__ __forceinline__ int RLI(int t, int d) {
  return ((t << 6) | d) ^ ((((t & 7) ^ ((t >> 3) & 7))) << 3);
}
__device__ __forceinline__ int SBI(int h, int t) {
  return ((h << 9) | t) ^ ((h & 7) << 3);
}

// ---------------- K1: SK = Q.K^T per (b,h), 64x64 tiles (proven) ----------
template <bool WSK>
__global__ __launch_bounds__(256, 4)
void qk_mfma(const float* __restrict__ Q, const float* __restrict__ K,
             void* __restrict__ skout) {
  const int bh   = blockIdx.x >> 6;
  const int tile = blockIdx.x & 63;
  const int s0 = (tile >> 3) << 6;
  const int t0 = (tile & 7) << 6;
  const int w    = threadIdx.x >> 6;
  const int lane = threadIdx.x & 63;
  const int rrow = lane & 15;
  const int kg   = lane >> 4;

  const float* Qb = Q + ((size_t)bh << 15);
  const float* Kb = K + ((size_t)bh << 15);

  const float* qp = Qb + (((s0 + (w << 4) + rrow) << 6) + (kg << 3));
  const short8 a0 = pack8(*reinterpret_cast<const float4*>(qp),
                          *reinterpret_cast<const float4*>(qp + 4));
  const short8 a1 = pack8(*reinterpret_cast<const float4*>(qp + 32),
                          *reinterpret_cast<const float4*>(qp + 36));

  float4 b0, b1, b2, b3;
  {
    const float* kp = Kb + (((t0 + rrow) << 6) + (kg << 3));
    b0 = *reinterpret_cast<const float4*>(kp);
    b1 = *reinterpret_cast<const float4*>(kp + 4);
    b2 = *reinterpret_cast<const float4*>(kp + 32);
    b3 = *reinterpret_cast<const float4*>(kp + 36);
  }
#pragma unroll
  for (int nt = 0; nt < 4; ++nt) {
    const short8 bb0 = pack8(b0, b1);
    const short8 bb1 = pack8(b2, b3);
    if (nt < 3) {
      const float* kp = Kb + (((t0 + ((nt + 1) << 4) + rrow) << 6) + (kg << 3));
      b0 = *reinterpret_cast<const float4*>(kp);
      b1 = *reinterpret_cast<const float4*>(kp + 4);
      b2 = *reinterpret_cast<const float4*>(kp + 32);
      b3 = *reinterpret_cast<const float4*>(kp + 36);
    }
    f32x4 c = {0.0f, 0.0f, 0.0f, 0.0f};
    c = MFMA16(a0, bb0, c);
    c = MFMA16(a1, bb1, c);
    const int tcol = t0 + (nt << 4) + rrow;
    const int srow = s0 + (w << 4) + (kg << 2);
    if constexpr (WSK) {
      unsigned short* ob = (unsigned short*)skout + ((size_t)bh << 18);
#pragma unroll
      for (int r = 0; r < 4; ++r)
        ob[(size_t)(srow + r) * 512 + tcol] = f2bf(c[r]);
    } else {
      float* ob = (float*)skout + ((size_t)bh << 18);
#pragma unroll
      for (int r = 0; r < 4; ++r)
        ob[(size_t)(srow + r) * 512 + tcol] = c[r];
    }
  }
}

// ---------------- K2: per (b,s): rel + softmax + ans2, 512 threads --------
template <bool WSK>
__global__ __launch_bounds__(512, 4)
void attn_v8(const float* __restrict__ Q, const float* __restrict__ R,
             const int* __restrict__ Mk, float* __restrict__ ans,
             float* __restrict__ pout, const void* __restrict__ skin) {
  __shared__ __align__(16) unsigned short smem[8 * 512 + 512 * 64];  // 72 KB
  __shared__ __align__(16) float Pp[4][8][16];                        // 2 KB
  unsigned short* Sb = smem;
  unsigned short* Rl = smem + 8 * 512;

  const int tid = threadIdx.x;
  const int b = blockIdx.x >> 9;
  const int s = blockIdx.x & 511;
  const int bh0 = b << 3;

  const float* Rg = R + ((size_t)((b << 9) + s) << 15);

  // ---- stage R[b,s] 512x64 fp32 -> Rl bf16 (swizzled), 8-deep batches ----
  {
    const int d4 = tid & 15;     // float4 col
    const int tr = tid >> 4;     // 0..31: row within 32-row stripe
#pragma unroll
    for (int pg = 0; pg < 2; ++pg) {
      float4 tmp[8];
#pragma unroll
      for (int j = 0; j < 8; ++j) {
        const int t = (pg << 8) + (j << 5) + tr;
        tmp[j] = *reinterpret_cast<const float4*>(Rg + (t << 6) + (d4 << 2));
      }
#pragma unroll
      for (int j = 0; j < 8; ++j) {
        const int t = (pg << 8) + (j << 5) + tr;
        unsigned short* dst = &Rl[RLI(t, d4 << 2)];
        dst[0] = f2bf(tmp[j].x); dst[1] = f2bf(tmp[j].y);
        dst[2] = f2bf(tmp[j].z); dst[3] = f2bf(tmp[j].w);
      }
    }
  }
  __syncthreads();

  const int lane = tid & 63;
  const int w    = tid >> 6;   // 0..7
  const int nn   = lane & 15;
  const int kg   = lane >> 4;

  // ---- rel[h,t] = Q[h,:].R[t,:] (A=Q padded to 16 rows, B=R) -> Sb ----
  {
    const int hq = nn & 7;
    const float* Qg = Q + ((size_t)(((bh0 + hq) << 9) + s) << 6);
    const short8 aq0 = pack8(*reinterpret_cast<const float4*>(Qg + (kg << 3)),
                             *reinterpret_cast<const float4*>(Qg + (kg << 3) + 4));
    const short8 aq1 = pack8(*reinterpret_cast<const float4*>(Qg + 32 + (kg << 3)),
                             *reinterpret_cast<const float4*>(Qg + 36 + (kg << 3)));

#pragma unroll
    for (int i = 0; i < 4; ++i) {
      const int t0 = ((w << 2) + i) << 4;
      const short8 bb0 = *reinterpret_cast<const short8*>(&Rl[RLI(t0 + nn, kg << 3)]);
      const short8 bb1 = *reinterpret_cast<const short8*>(&Rl[RLI(t0 + nn, 32 + (kg << 3))]);
      f32x4 c = {0.0f, 0.0f, 0.0f, 0.0f};
      c = MFMA16(aq0, bb0, c);
      c = MFMA16(aq1, bb1, c);
      if (kg < 2) {
#pragma unroll
        for (int r = 0; r < 4; ++r)
          Sb[SBI((kg << 2) + r, t0 + nn)] = f2bf(c[r]);
      }
    }
  }
  __syncthreads();

  // ---- softmax row h = w: (rel + SK)/8 + mask -> p ----
  {
    const int h = w;
    float bias[8];
#pragma unroll
    for (int k = 0; k < 8; ++k)
      bias[k] = Mk[(b << 9) + lane + (k << 6)] ? 0.0f : -1.0e9f;

    float* po = pout + ((size_t)(bh0 + h) << 18) + ((size_t)s << 9);
    const unsigned short* skw =
        WSK ? (const unsigned short*)skin + ((size_t)(bh0 + h) << 18) + ((size_t)s << 9)
            : nullptr;
    const float* skf =
        WSK ? nullptr
            : (const float*)skin + ((size_t)(bh0 + h) << 18) + ((size_t)s << 9);

    float v[8];
#pragma unroll
    for (int k = 0; k < 8; ++k) {
      const int t = lane + (k << 6);
      const float skv = WSK ? bf2f((unsigned int)skw[t]) : skf[t];
      v[k] = (bf2f((unsigned int)Sb[SBI(h, t)]) + skv) * 0.125f + bias[k];
    }
    float m = v[0];
#pragma unroll
    for (int k = 1; k < 8; ++k) m = fmaxf(m, v[k]);
    m = fmaxf(m, __shfl_xor(m, 1));
    m = fmaxf(m, __shfl_xor(m, 2));
    m = fmaxf(m, __shfl_xor(m, 4));
    m = fmaxf(m, __shfl_xor(m, 8));
    m = fmaxf(m, __shfl_xor(m, 16));
    m = fmaxf(m, __shfl_xor(m, 32));

    float e[8], ss = 0.0f;
#pragma unroll
    for (int k = 0; k < 8; ++k) { e[k] = __expf(v[k] - m); ss += e[k]; }
    ss += __shfl_xor(ss, 1);
    ss += __shfl_xor(ss, 2);
    ss += __shfl_xor(ss, 4);
    ss += __shfl_xor(ss, 8);
    ss += __shfl_xor(ss, 16);
    ss += __shfl_xor(ss, 32);
    const float inv = 1.0f / ss;

#pragma unroll
    for (int k = 0; k < 8; ++k) {
      const float p = e[k] * inv;
      const int t = lane + (k << 6);
      po[t] = p;
      Sb[SBI(h, t)] = f2bf(p);
    }
  }
  __syncthreads();

  // ---- ans2[h,d] = sum_t P[h,t].R[t,d]; 8-wave split (d-tile, k-half) ----
  {
    const int dt = w & 3;        // d-tile: cols dt*16..dt*16+15
    const int kh = w >> 2;       // k-half: ks 8*kh..8*kh+7
    const int n0 = dt << 4;

    f32x4 acc = {0.0f, 0.0f, 0.0f, 0.0f};
#pragma unroll
    for (int k8 = 0; k8 < 8; ++k8) {
      const int tb = (((kh << 3) + k8) << 5) + (kg << 3);
      const short8 af = *reinterpret_cast<const short8*>(&Sb[SBI(nn, tb)]);
      short8 bf;
#pragma unroll
      for (int j = 0; j < 8; ++j)
        bf[j] = (short)Rl[RLI(tb + j, n0 + nn)];
      acc = MFMA16(af, bf, acc);
    }
    if (kh == 1 && kg < 2) {
#pragma unroll
      for (int r = 0; r < 4; ++r)
        Pp[dt][(kg << 2) + r][nn] = acc[r];
    }
    __syncthreads();
    if (kh == 0 && kg < 2) {
#pragma unroll
      for (int r = 0; r < 4; ++r) {
        const int h = (kg << 2) + r;
        ans[((size_t)(((bh0 + h) << 9) + s) << 6) + n0 + nn] =
            acc[r] + Pp[dt][h][nn];
      }
    }
  }
}

// ---------------- K3: ans += P.V per (b,h,32-row s-tile), 512 threads -----
__global__ __launch_bounds__(512, 4)
void pv_mfma(const float* __restrict__ V, const float* __restrict__ pout,
             float* __restrict__ ans) {
  __shared__ __align__(16) unsigned short Vl[512 * 64];   // 64 KB

  const int tid = threadIdx.x;
  const int bh = blockIdx.x >> 4;
  const int s0 = (blockIdx.x & 15) << 5;

  const float* Vg = V + ((size_t)bh << 15);
  {
    const int d4 = tid & 15;
    const int tr = tid >> 4;     // 0..31
#pragma unroll
    for (int pg = 0; pg < 2; ++pg) {
      float4 tmp[8];
#pragma unroll
      for (int j = 0; j < 8; ++j) {
        const int t = (pg << 8) + (j << 5) + tr;
        tmp[j] = *reinterpret_cast<const float4*>(Vg + (t << 6) + (d4 << 2));
      }
#pragma unroll
      for (int j = 0; j < 8; ++j) {
        const int t = (pg << 8) + (j << 5) + tr;
        unsigned short* dst = &Vl[RLI(t, d4 << 2)];
        dst[0] = f2bf(tmp[j].x); dst[1] = f2bf(tmp[j].y);
        dst[2] = f2bf(tmp[j].z); dst[3] = f2bf(tmp[j].w);
      }
    }
  }
  __syncthreads();

  const int lane = tid & 63;
  const int w    = tid >> 6;     // 0..7
  const int nn   = lane & 15;
  const int kg   = lane >> 4;
  const int rw   = w & 1;        // s-subtile (16 rows)
  const int cq   = w >> 1;       // d-tile: cols cq*16..cq*16+15
  const int n0   = cq << 4;
  const int srow = s0 + (rw << 4) + nn;

  const float* Pg = pout + ((size_t)bh << 18) + ((size_t)srow << 9);

  f32x4 acc = {0.f, 0.f, 0.f, 0.f};

  float4 pa = *reinterpret_cast<const float4*>(Pg + (kg << 3));
  float4 pb = *reinterpret_cast<const float4*>(Pg + (kg << 3) + 4);
#pragma unroll
  for (int ks = 0; ks < 16; ++ks) {
    const short8 af = pack8(pa, pb);
    if (ks < 15) {
      pa = *reinterpret_cast<const float4*>(Pg + ((ks + 1) << 5) + (kg << 3));
      pb = *reinterpret_cast<const float4*>(Pg + ((ks + 1) << 5) + (kg << 3) + 4);
    }
    const int tb = (ks << 5) + (kg << 3);
    short8 bf;
#pragma unroll
    for (int j = 0; j < 8; ++j)
      bf[j] = (short)Vl[RLI(tb + j, n0 + nn)];
    acc = MFMA16(af, bf, acc);
  }

  {
    const int sb = s0 + (rw << 4) + (kg << 2);
#pragma unroll
    for (int r = 0; r < 4; ++r) {
      float* ap = ans + ((size_t)bh << 15) + ((size_t)(sb + r) << 6) + n0 + nn;
      ap[0] += acc[r];
    }
  }
}

extern "C" void kernel_launch(void* const* d_in, const int* in_sizes, int n_in,
                              void* d_out, int out_size, void* d_ws, size_t ws_size,
                              hipStream_t stream) {
  const float* Q  = (const float*)d_in[0];
  const float* K  = (const float*)d_in[1];
  const float* V  = (const float*)d_in[2];
  const float* R  = (const float*)d_in[3];
  const int*   Mk = (const int*)d_in[4];
  float* ans  = (float*)d_out;
  float* pout = ans + (size_t)4 * 8 * 512 * 64;  // p_attn region
  (void)in_sizes; (void)n_in; (void)out_size;

  const size_t sk_bf16_bytes = (size_t)4 * 8 * 512 * 512 * 2;  // 16.8 MB

  if (ws_size >= sk_bf16_bytes) {
    hipLaunchKernelGGL((qk_mfma<true>), dim3(2048), dim3(256), 0, stream,
                       Q, K, d_ws);
    hipLaunchKernelGGL((attn_v8<true>), dim3(2048), dim3(512), 0, stream,
                       Q, R, Mk, ans, pout, d_ws);
  } else {
    hipLaunchKernelGGL((qk_mfma<false>), dim3(2048), dim3(256), 0, stream,
                       Q, K, pout);
    hipLaunchKernelGGL((attn_v8<false>), dim3(2048), dim3(512), 0, stream,
                       Q, R, Mk, ans, pout, pout);
  }
  hipLaunchKernelGGL(pv_mfma, dim3(512), dim3(512), 0, stream, V, pout, ans);
}